// Round 1
// baseline (1420.163 us; speedup 1.0000x reference)
//
#include <hip/hip_runtime.h>

// Problem constants (setup_inputs fixed: x=(2,256,512,512) fp32, H=W=512)
#define BB 2
#define CC 256
#define HH 512
#define WW 512
#define PS 52               // patch size: min(int(512*0.1)+1, ...) = 52
#define NW 9                // patches per row/col
#define NP 81               // patches total
#define COV 468             // covered extent = 9*52
#define PLANE (HH*WW)       // 262144
#define CHW (CC*PLANE)
#define SP (PS*PS)          // 2704

// ---------------- K1: per-(b,c) plane sums (for GAP) ----------------
__global__ __launch_bounds__(256) void gap_kernel(const float* __restrict__ x,
                                                  float* __restrict__ gsum) {
    int plane = blockIdx.x;  // 0..511  == b*256 + ch
    const float4* p = (const float4*)(x + (size_t)plane * PLANE);
    float acc = 0.f;
    for (int i = threadIdx.x; i < PLANE / 4; i += 256) {
        float4 v = p[i];
        acc += v.x + v.y + v.z + v.w;
    }
    __shared__ float red[256];
    red[threadIdx.x] = acc;
    __syncthreads();
    for (int s = 128; s > 0; s >>= 1) {
        if (threadIdx.x < s) red[threadIdx.x] += red[threadIdx.x + s];
        __syncthreads();
    }
    if (threadIdx.x == 0) gsum[plane] = red[0];
}

// ---------------- K2: per-(b,l,cg) binned sums T + sum of squares ----------------
// Weight bin for u-channel d_u = ch*2704 + s is d_u mod 256 = (144*ch + s) & 255.
// For s = tid + 256k the bin is constant per (ch, tid): no atomics needed.
// Wave-private LDS copies avoid cross-wave RMW races; fully deterministic.
__global__ __launch_bounds__(256) void stats_kernel(const float* __restrict__ x,
                                                    float* __restrict__ T,
                                                    float* __restrict__ pn) {
    int cg = blockIdx.x;   // 0..7  (32-channel group)
    int l  = blockIdx.y;   // 0..80
    int b  = blockIdx.z;   // 0..1
    int ph = l / NW, pw = l - ph * NW;
    int tid = threadIdx.x;
    int wv = tid >> 6;

    __shared__ float Tpart[4][256];
    #pragma unroll
    for (int w = 0; w < 4; w++) Tpart[w][tid] = 0.f;
    __syncthreads();

    float pacc = 0.f;
    const float* base_b = x + (size_t)b * CHW + (size_t)(ph * PS) * WW + (pw * PS);
    for (int ci = 0; ci < 32; ci++) {
        int ch = cg * 32 + ci;
        const float* base = base_b + (size_t)ch * PLANE;
        float a = 0.f;
        for (unsigned s = tid; s < SP; s += 256) {
            unsigned kh = s / PS;
            unsigned kw = s - kh * PS;
            float v = base[kh * WW + kw];
            a += v;
            pacc += v * v;
        }
        int bin = (144 * ch + tid) & 255;
        Tpart[wv][bin] += a;   // distinct bin per lane within wave -> race-free
    }
    __syncthreads();

    float tsum = Tpart[0][tid] + Tpart[1][tid] + Tpart[2][tid] + Tpart[3][tid];
    T[(((size_t)b * NP + l) * 8 + cg) * 256 + tid] = tsum;

    __shared__ float red[256];
    red[tid] = pacc;
    __syncthreads();
    for (int s2 = 128; s2 > 0; s2 >>= 1) {
        if (tid < s2) red[tid] += red[tid + s2];
        __syncthreads();
    }
    if (tid == 0) pn[((size_t)b * NP + l) * 8 + cg] = red[0];
}

// ---------------- K3: cosine + argmax/argmin selection ----------------
__global__ __launch_bounds__(256) void select_kernel(const float* __restrict__ gsum,
                                                     const float* __restrict__ T,
                                                     const float* __restrict__ pn,
                                                     int* __restrict__ sel) {
    int b = blockIdx.x;
    int t = threadIdx.x;
    float g = gsum[b * 256 + t] * (1.0f / PLANE);

    __shared__ float red[256];
    red[t] = g * g;
    __syncthreads();
    for (int s = 128; s > 0; s >>= 1) {
        if (t < s) red[t] += red[t + s];
        __syncthreads();
    }
    float gnorm = sqrtf(red[0]) * (float)PS;
    __syncthreads();

    float best = -1e30f, worst = 1e30f;
    int bi = 0, wi = 0;
    for (int l = 0; l < NP; l++) {
        const float* Tl = T + ((size_t)b * NP + l) * 8 * 256;
        float d = 0.f;
        #pragma unroll
        for (int cg = 0; cg < 8; cg++) d += Tl[cg * 256 + t];
        d *= g;
        red[t] = d;
        __syncthreads();
        for (int s = 128; s > 0; s >>= 1) {
            if (t < s) red[t] += red[t + s];
            __syncthreads();
        }
        if (t == 0) {
            float pacc = 0.f;
            #pragma unroll
            for (int cg = 0; cg < 8; cg++) pacc += pn[((size_t)b * NP + l) * 8 + cg];
            float pnorm = sqrtf(pacc);
            float cosv = red[0] / fmaxf(gnorm * pnorm, 1e-8f);
            if (cosv > best) { best = cosv; bi = l; }   // strict > keeps first (jnp.argmax)
            if (cosv < worst) { worst = cosv; wi = l; } // strict < keeps first (argmin)
        }
        __syncthreads();
    }
    if (t == 0) { sel[b * 2 + 0] = bi; sel[b * 2 + 1] = wi; }
}

// ---------------- K4: apply — per-patch 2704x256 transpose-gather * x ----------------
// mask[ch', s of patch l] = x[src_patch, patch-flat d_u = s*256 + ch'] ; out = mask * x.
// 64(s) x 64(ch') LDS tile: load coalesced over d_u, store coalesced over s.
__global__ __launch_bounds__(256) void apply_kernel(const float* __restrict__ x,
                                                    float* __restrict__ out,
                                                    const int* __restrict__ sel) {
    int tile = blockIdx.x;      // 0..171 = tc(4) * ts(43)
    int tc = tile / 43;         // ch' tile
    int ts = tile - tc * 43;    // s tile
    int l = blockIdx.y;
    int b = blockIdx.z;
    int ph = l / NW, pw = l - ph * NW;
    int idx = sel[b * 2 + 0], ids = sel[b * 2 + 1];
    int sl_patch = (l == idx) ? ids : l;
    int sph = sl_patch / NW, spw = sl_patch - sph * NW;

    const float* xb = x + (size_t)b * CHW;
    const float* src_base = xb + (size_t)(sph * PS) * WW + (spw * PS);

    __shared__ float tilebuf[64][65];
    int cb = tc * 64;
    int sb = ts * 64;
    int t = threadIdx.x;

    {   // load: lanes sweep ch' (consecutive d_u -> coalesced-ish source reads)
        int cl = t & 63;
        int sr = t >> 6;
        #pragma unroll
        for (int i = 0; i < 16; i++) {
            int s_l = i * 4 + sr;
            int s_g = sb + s_l;
            float v = 0.f;
            if (s_g < SP) {
                unsigned du = (unsigned)s_g * 256u + (unsigned)(cb + cl);
                unsigned chs = du / SP;
                unsigned rem = du - chs * SP;
                unsigned kh = rem / PS;
                unsigned kw = rem - kh * PS;
                v = src_base[(size_t)chs * PLANE + kh * WW + kw];
            }
            tilebuf[s_l][cl] = v;
        }
    }
    __syncthreads();
    {   // store: lanes sweep s (contiguous w runs) ; multiply by x at out position
        int sl = t & 63;
        int cr = t >> 6;
        int s_g = sb + sl;
        if (s_g < SP) {
            unsigned sh = (unsigned)s_g / PS;
            unsigned sw = (unsigned)s_g - sh * PS;
            size_t pos = (size_t)(ph * PS + sh) * WW + (pw * PS + sw);
            #pragma unroll
            for (int i = 0; i < 16; i++) {
                int c_l = i * 4 + cr;
                size_t off = (size_t)(cb + c_l) * PLANE + pos;
                out[(size_t)b * CHW + off] = tilebuf[sl][c_l] * xb[off];
            }
        }
    }
}

// ---------------- K5: zero the uncovered border ----------------
// Per plane: right strip (all h, w in [468,512)) = 512*11 float4,
// bottom strip (h in [468,512), w in [0,468)) = 44*117 float4. Total 10780.
__global__ __launch_bounds__(256) void border_kernel(float* __restrict__ out) {
    int plane = blockIdx.y;   // 0..1023
    int t = blockIdx.x * 256 + threadIdx.x;
    if (t >= 10780) return;
    float4* p = (float4*)(out + (size_t)plane * PLANE);
    int idx4;
    if (t < 5632) {
        int row = t / 11;
        int col = t - row * 11;
        idx4 = row * 128 + 117 + col;
    } else {
        int t2 = t - 5632;
        int row = t2 / 117;
        int col = t2 - row * 117;
        idx4 = (COV + row) * 128 + col;
    }
    p[idx4] = make_float4(0.f, 0.f, 0.f, 0.f);
}

extern "C" void kernel_launch(void* const* d_in, const int* in_sizes, int n_in,
                              void* d_out, int out_size, void* d_ws, size_t ws_size,
                              hipStream_t stream) {
    const float* x = (const float*)d_in[0];
    float* out = (float*)d_out;
    float* ws = (float*)d_ws;

    // workspace layout (floats): T[2*81*8*256] | pn[2*81*8] | gsum[512] | sel(4 ints)
    float* T    = ws;                    // 331776 floats
    float* pn   = ws + 331776;           // 1296 floats
    float* gsum = ws + 333072;           // 512 floats
    int*   sel  = (int*)(ws + 333584);   // 4 ints
    // total ~1.28 MB; every slot rewritten each call (no zero-init needed)

    gap_kernel<<<dim3(BB * CC), dim3(256), 0, stream>>>(x, gsum);
    stats_kernel<<<dim3(8, NP, BB), dim3(256), 0, stream>>>(x, T, pn);
    select_kernel<<<dim3(BB), dim3(256), 0, stream>>>(gsum, T, pn, sel);
    apply_kernel<<<dim3(172, NP, BB), dim3(256), 0, stream>>>(x, out, sel);
    border_kernel<<<dim3(43, BB * CC), dim3(256), 0, stream>>>(out);
}